// Round 1
// baseline (228.352 us; speedup 1.0000x reference)
//
#include <hip/hip_runtime.h>

#define S_VOX (128*128*128)   // spatial voxels per (b,n) plane = 2097152
#define QV (S_VOX/4)          // float4 groups per plane
#define EPSF 1e-10f
#define SMOOTHF 1e-5f

// ws layout (floats): [0] ce_sum, [1+ b*8+n] inter, [17+ b*8+n] ground, [33+ b*8+n] pred_o
#define NACC 49

__device__ __forceinline__ float wave_reduce(float v) {
#pragma unroll
    for (int off = 32; off > 0; off >>= 1)
        v += __shfl_down(v, off, 64);
    return v;
}

__global__ __launch_bounds__(256) void dice_main(const float* __restrict__ pred,
                                                 const int* __restrict__ tgt,
                                                 float* __restrict__ ws) {
    const float4* p4 = (const float4*)pred;
    const int4*   t4 = (const int4*)tgt;

    float ce = 0.f;
    float inter[2][8];
    float po[2][8];
    int   gc[2][8];
#pragma unroll
    for (int b = 0; b < 2; b++)
#pragma unroll
        for (int n = 0; n < 8; n++) { inter[b][n] = 0.f; po[b][n] = 0.f; gc[b][n] = 0; }

    const int tid    = blockIdx.x * blockDim.x + threadIdx.x;
    const int stride = gridDim.x * blockDim.x;

    for (int q = tid; q < QV; q += stride) {
        const int4 t0 = t4[q];        // batch 0 targets, 4 voxels
        const int4 t1 = t4[QV + q];   // batch 1 targets
#pragma unroll
        for (int n = 0; n < 8; n++) {
            const float4 a = p4[n * QV + q];        // pred[0][n], 4 voxels
            const float4 b = p4[(8 + n) * QV + q];  // pred[1][n], 4 voxels

            // pred_o: unconditional sums
            po[0][n] += (a.x + a.y) + (a.z + a.w);
            po[1][n] += (b.x + b.y) + (b.z + b.w);

            // per-voxel masked accumulation (n is a compile-time constant here)
#define VOXEL(pa, pb, ta, tb)                                              \
            {                                                              \
                float lg = __logf((pa) + EPSF) + __logf((pb) + EPSF);      \
                int m0 = ((ta) == n);                                      \
                int m1 = ((tb) == n);                                      \
                ce += lg * (float)(m0 + m1);                               \
                inter[0][n] += m0 ? (pa) : 0.f;                            \
                inter[1][n] += m1 ? (pb) : 0.f;                            \
                gc[0][n] += m0;                                            \
                gc[1][n] += m1;                                            \
            }
            VOXEL(a.x, b.x, t0.x, t1.x)
            VOXEL(a.y, b.y, t0.y, t1.y)
            VOXEL(a.z, b.z, t0.z, t1.z)
            VOXEL(a.w, b.w, t0.w, t1.w)
#undef VOXEL
        }
    }

    // pack accumulators
    float acc[NACC];
    acc[0] = ce;
#pragma unroll
    for (int b = 0; b < 2; b++)
#pragma unroll
        for (int n = 0; n < 8; n++) {
            acc[1  + b * 8 + n] = inter[b][n];
            acc[17 + b * 8 + n] = (float)gc[b][n];
            acc[33 + b * 8 + n] = po[b][n];
        }

    __shared__ float red[4][NACC];
    const int lane = threadIdx.x & 63;
    const int wave = threadIdx.x >> 6;
#pragma unroll
    for (int i = 0; i < NACC; i++) {
        float v = wave_reduce(acc[i]);
        if (lane == 0) red[wave][i] = v;
    }
    __syncthreads();
    if (threadIdx.x < NACC) {
        float s = red[0][threadIdx.x] + red[1][threadIdx.x] +
                  red[2][threadIdx.x] + red[3][threadIdx.x];
        atomicAdd(&ws[threadIdx.x], s);
    }
}

__global__ void dice_finalize(const float* __restrict__ ws, float* __restrict__ out) {
    const int i = threadIdx.x;
    float term = 0.f;
    if (i < 16) {
        float inter = ws[1 + i];
        float g     = ws[17 + i];
        float p     = ws[33 + i];
        term = 1.0f - (2.0f * inter + SMOOTHF) / (g + p + SMOOTHF);
    }
    term = wave_reduce(term);
    if (i == 0) {
        // celoss = -ce_sum / (B*B*S)  with B=2
        float celoss = -ws[0] / (4.0f * (float)S_VOX);
        out[0] = celoss + term * (1.0f / 16.0f);
    }
}

extern "C" void kernel_launch(void* const* d_in, const int* in_sizes, int n_in,
                              void* d_out, int out_size, void* d_ws, size_t ws_size,
                              hipStream_t stream) {
    const float* pred = (const float*)d_in[0];
    const int*   tgt  = (const int*)d_in[1];
    float* ws  = (float*)d_ws;
    float* out = (float*)d_out;

    hipMemsetAsync(ws, 0, NACC * sizeof(float), stream);
    dice_main<<<1024, 256, 0, stream>>>(pred, tgt, ws);
    dice_finalize<<<1, 64, 0, stream>>>(ws, out);
}